// Round 5
// baseline (853.133 us; speedup 1.0000x reference)
//
#include <hip/hip_runtime.h>

#define B_ 16
#define S_ 512
#define T_ 2048
#define D_ 256
#define H_ 128

typedef _Float16 half2_t __attribute__((ext_vector_type(2)));
union U32H2 { unsigned u; half2_t h; };
union UH16 { _Float16 f; unsigned short u; };

// ---------------- workspace layout (floats) ----------------
#define WS_C     0          // c centers [B,S] : 8192
#define WS_W2    8192       // w2 [B,T] : 32768
#define WS_WPK   40960      // Whh f16-pair pack [2 layers][65536 uint] : 131072 uints
#define WS_XG    303104     // Xg [dir][s][b][512] fp32 : 8388608
#define WS_H1    8691712    // H [b][s][256] fp32 : 2097152

// ---------------- output layout (floats) ----------------
#define OUT_MAIN   0          // [B,T,D]  8388608
#define OUT_LOGDUR 8388608    // [B,S]    8192
#define OUT_DUR    8396800    // [B,S]    8192
#define OUT_W      8404992    // [B,S,T]  16777216

__device__ __forceinline__ float sigf(float x) { return 1.f / (1.f + __expf(-x)); }
__device__ __forceinline__ float tanhfast(float x) {
    float xc = fmaxf(x, -15.f);
    float e = __expf(-2.f * xc);
    return (1.f - e) / (1.f + e);
}

// quad_perm DPP lane swap within each 4-lane quad (VALU pipe, not LDS)
template <int CTRL>
__device__ __forceinline__ float qswap(float v) {
    int i = __builtin_bit_cast(int, v);
    i = __builtin_amdgcn_update_dpp(0, i, CTRL, 0xf, 0xf, true);
    return __builtin_bit_cast(float, i);
}
#define QP_XOR1 0xB1  // [1,0,3,2]
#define QP_XOR2 0x4E  // [2,3,0,1]
#define QP_XOR3 0x1B  // [3,2,1,0]

// ============ prep: cumsum -> centers, copy duration ============
__global__ void prep_kernel(const float* __restrict__ dur, float* __restrict__ c,
                            float* __restrict__ out_dur) {
    int b = blockIdx.x;
    int s = threadIdx.x;
    __shared__ float sc[S_];
    float d = dur[b * S_ + s];
    sc[s] = d;
    __syncthreads();
    float v = d;
    for (int off = 1; off < S_; off <<= 1) {
        float add = (s >= off) ? sc[s - off] : 0.f;
        __syncthreads();
        v += add;
        sc[s] = v;
        __syncthreads();
    }
    c[b * S_ + s] = v - 0.5f * d;
    out_dur[b * S_ + s] = d;
}

// ============ Whh -> f16 pack for quad-K-split scan ============
// uidx = ((layer*2+dir)*512 + st)*64 + g*16 + kk ; st = e*4+q
// value = pair(W[row=g*128+e][2*(q*16+kk)], W[row][2*(q*16+kk)+1])
__global__ void whh_pack_kernel(const float* __restrict__ Whh0, const float* __restrict__ Whh1,
                                unsigned* __restrict__ wpk) {
    int idx = blockIdx.x * 256 + threadIdx.x;  // 131072
    int kk = idx & 15, g = (idx >> 4) & 3, st = (idx >> 6) & 511;
    int dir = (idx >> 15) & 1, layer = (idx >> 16) & 1;
    int e = st >> 2, q = st & 3;
    int row = g * 128 + e;
    int k2 = q * 16 + kk;
    const float* W = layer ? Whh1 : Whh0;
    float lo = W[dir * 65536 + row * 128 + 2 * k2];
    float hi = W[dir * 65536 + row * 128 + 2 * k2 + 1];
    U32H2 u;
    u.h = half2_t{(_Float16)lo, (_Float16)hi};
    wpk[idx] = u.u;
}

// ============ gemm: Xg[((dir*512+s)*16+b)*512+jj] = A[m,:256].Wih[n,:256]+bias ============
// A rows m = b*512+s  (x is [B,S,256]; H1 is [b][s][256] -> same row order)
#define BM 64
#define BN 64
#define BK 64
__global__ __launch_bounds__(256) void gemm_xg_kernel(const float* __restrict__ A,
                                                      const float* __restrict__ Bw,
                                                      const float* __restrict__ bias,
                                                      float* __restrict__ Xg) {
    __shared__ float As[BK][BM + 4];
    __shared__ float Bs[BK][BN + 4];
    int tid = threadIdx.x;
    int m0 = blockIdx.x * BM;
    int n0 = blockIdx.y * BN;
    int tm = tid >> 4, tn = tid & 15;
    float acc[4][4] = {};
    for (int k0 = 0; k0 < 256; k0 += BK) {
#pragma unroll
        for (int i = 0; i < 4; i++) {
            int p = tid + 256 * i;
            int m = p >> 4, kq = p & 15;
            float4 av = *reinterpret_cast<const float4*>(&A[(size_t)(m0 + m) * 256 + k0 + 4 * kq]);
            As[4 * kq + 0][m] = av.x; As[4 * kq + 1][m] = av.y;
            As[4 * kq + 2][m] = av.z; As[4 * kq + 3][m] = av.w;
            float4 bv = *reinterpret_cast<const float4*>(&Bw[(size_t)(n0 + m) * 256 + k0 + 4 * kq]);
            Bs[4 * kq + 0][m] = bv.x; Bs[4 * kq + 1][m] = bv.y;
            Bs[4 * kq + 2][m] = bv.z; Bs[4 * kq + 3][m] = bv.w;
        }
        __syncthreads();
#pragma unroll
        for (int k = 0; k < BK; k++) {
            float4 a4 = *reinterpret_cast<const float4*>(&As[k][4 * tm]);
            float4 b4 = *reinterpret_cast<const float4*>(&Bs[k][4 * tn]);
            float av[4] = {a4.x, a4.y, a4.z, a4.w};
            float bv[4] = {b4.x, b4.y, b4.z, b4.w};
#pragma unroll
            for (int i = 0; i < 4; i++)
#pragma unroll
                for (int j = 0; j < 4; j++) acc[i][j] += av[i] * bv[j];
        }
        __syncthreads();
    }
#pragma unroll
    for (int i = 0; i < 4; i++) {
        int m = m0 + 4 * tm + i;
        int b = m >> 9, s = m & 511;
#pragma unroll
        for (int jx = 0; jx < 4; jx++) {
            int n = n0 + 4 * tn + jx;
            int dir = n >> 9, jj = n & 511;
            Xg[((size_t)(dir * 512 + s) * 16 + b) * 512 + jj] = acc[i][jx] + bias[n];
        }
    }
}

// ============ LSTM scan body: quad-K-split, 512 threads, 1 barrier/step ============
// thread st = e*4+q: K-quarter q of gate rows {e,128+e,256+e,384+e}
__device__ void lstm_scan_body(const float* __restrict__ Xg, const unsigned* __restrict__ wpk,
                               float* __restrict__ Hout, char* smem, int blk) {
    int dir = blk >> 4;
    int b = blk & 15;
    int st = threadIdx.x;
    int e = st >> 2, q = st & 3;

    // weights: 16 uint4 = 64 VGPRs, pinned so the compiler can't re-stream them
    uint4 wv[16];
    const uint4* wp = (const uint4*)(wpk + ((size_t)dir * 512 + st) * 64);
#pragma unroll
    for (int i = 0; i < 16; i++) wv[i] = wp[i];
#pragma unroll
    for (int i = 0; i < 16; i++)
        asm volatile("" : "+v"(wv[i].x), "+v"(wv[i].y), "+v"(wv[i].z), "+v"(wv[i].w));

    unsigned short* hb = (unsigned short*)smem;  // [2][128] f16, double-buffered
    if (st < 128) hb[st] = 0;                    // h_{-1} = 0 in buffer 0

    const float* xg_base = Xg + (size_t)dir * (512 * 16 * 512) + (size_t)b * 512 + q * 128 + e;
    int s0 = dir ? 511 : 0;
    float xg_cur = xg_base[(size_t)s0 * 8192];
    float c = 0.f;
    __syncthreads();

    for (int t = 0; t < 512; t++) {
        int s = dir ? 511 - t : t;
        int t2 = (t < 511) ? t + 1 : 511;
        int s2 = dir ? 511 - t2 : t2;
        float xg_next = xg_base[(size_t)s2 * 8192];  // prefetch (never drained in-loop)

        // h quarter: 4 x ds_read_b128
        const uint4* h4 = (const uint4*)(hb + (t & 1) * 128 + q * 32);
        uint4 h0 = h4[0], h1 = h4[1], h2 = h4[2], h3 = h4[3];

        float a0 = 0.f, a1 = 0.f, a2 = 0.f, a3 = 0.f;
#define DOT4(ACC, W0, HH)                                                     \
        { U32H2 wa, wb, wc, wd, xa, xb, xc, xd;                               \
          wa.u = wv[W0].x; wb.u = wv[W0].y; wc.u = wv[W0].z; wd.u = wv[W0].w; \
          xa.u = HH.x; xb.u = HH.y; xc.u = HH.z; xd.u = HH.w;                 \
          ACC = __builtin_amdgcn_fdot2(xa.h, wa.h, ACC, false);               \
          ACC = __builtin_amdgcn_fdot2(xb.h, wb.h, ACC, false);               \
          ACC = __builtin_amdgcn_fdot2(xc.h, wc.h, ACC, false);               \
          ACC = __builtin_amdgcn_fdot2(xd.h, wd.h, ACC, false); }
        DOT4(a0, 0, h0) DOT4(a0, 1, h1) DOT4(a0, 2, h2) DOT4(a0, 3, h3)
        DOT4(a1, 4, h0) DOT4(a1, 5, h1) DOT4(a1, 6, h2) DOT4(a1, 7, h3)
        DOT4(a2, 8, h0) DOT4(a2, 9, h1) DOT4(a2, 10, h2) DOT4(a2, 11, h3)
        DOT4(a3, 12, h0) DOT4(a3, 13, h1) DOT4(a3, 14, h2) DOT4(a3, 15, h3)
#undef DOT4

        // quad butterfly: full sums in all 4 lanes (DPP, VALU pipe)
        a0 += qswap<QP_XOR1>(a0); a0 += qswap<QP_XOR2>(a0);
        a1 += qswap<QP_XOR1>(a1); a1 += qswap<QP_XOR2>(a1);
        a2 += qswap<QP_XOR1>(a2); a2 += qswap<QP_XOR2>(a2);
        a3 += qswap<QP_XOR1>(a3); a3 += qswap<QP_XOR2>(a3);

        float gfull = (q == 0 ? a0 : q == 1 ? a1 : q == 2 ? a2 : a3) + xg_cur;
        float act = (q == 2) ? tanhfast(gfull) : sigf(gfull);

        // gather quad activations into q==0 lanes: act=i, xf=f, xg2=g, xo=o
        float xf = qswap<QP_XOR1>(act);
        float xg2 = qswap<QP_XOR2>(act);
        float xo = qswap<QP_XOR3>(act);

        float cn = xf * c + act * xg2;  // valid in q==0 lanes
        c = cn;
        float h = xo * tanhfast(cn);

        if (q == 0) {
            UH16 hv; hv.f = (_Float16)h;
            hb[((t + 1) & 1) * 128 + e] = hv.u;
            Hout[((size_t)b * 512 + s) * 256 + dir * 128 + e] = h;
        }
        // make ds_write visible; do NOT drain vmcnt (stores + xg prefetch in flight)
        asm volatile("s_waitcnt lgkmcnt(0)\n\ts_barrier" ::: "memory");
        xg_cur = xg_next;
    }
}

// ============ w-write body (fused into layer-0 scan launch) ============
__device__ void wwrite_body(const float* __restrict__ c, const float* __restrict__ w2,
                            float* __restrict__ wout, int gb) {
    int base = (gb * 512 + (int)threadIdx.x) * 8;
    int t0 = base & 2047;
    int bs = base >> 11;
    int b = bs >> 9;
    float cv = c[bs];
    float4 w2a = *(const float4*)&w2[b * 2048 + t0];
    float4 w2b = *(const float4*)&w2[b * 2048 + t0 + 4];
    float r[8];
#pragma unroll
    for (int i = 0; i < 8; i++) {
        float d = (float)(t0 + 1 + i) - cv;
        r[i] = __expf(-0.1f * d * d);
    }
    float4 o1 = {r[0] / w2a.x, r[1] / w2a.y, r[2] / w2a.z, r[3] / w2a.w};
    float4 o2 = {r[4] / w2b.x, r[5] / w2b.y, r[6] / w2b.z, r[7] / w2b.w};
    *(float4*)&wout[base] = o1;
    *(float4*)&wout[base + 4] = o2;
}

// ============ einsum GEMM body, 512 threads, 128(t)x64(d) fp32 tile ============
__device__ void gemm_out_body(const float* __restrict__ wmat, const float* __restrict__ x,
                              float* __restrict__ out, int gb, char* smem) {
    int tt = gb & 15, dd = (gb >> 4) & 3, b = gb >> 6;
    int m0 = tt * 128, n0 = dd * 64;
    float* As = (float*)smem;        // [64][132]
    float* Bs = As + 64 * 132;       // [64][68]
    const float* wb = wmat + (size_t)b * (512 * 2048);
    const float* xb = x + (size_t)b * (512 * 256);
    int tid = threadIdx.x;
    int tm = tid >> 4, tn = tid & 15;
    float acc[4][4] = {};
    for (int k0 = 0; k0 < 512; k0 += 64) {
#pragma unroll
        for (int i = 0; i < 4; i++) {
            int p = tid + 512 * i;
            int kk = p >> 5, mq = p & 31;
            *(float4*)&As[kk * 132 + 4 * mq] =
                *(const float4*)&wb[(size_t)(k0 + kk) * 2048 + m0 + 4 * mq];
        }
#pragma unroll
        for (int i = 0; i < 2; i++) {
            int p = tid + 512 * i;
            int kk = p >> 4, nq = p & 15;
            *(float4*)&Bs[kk * 68 + 4 * nq] =
                *(const float4*)&xb[(size_t)(k0 + kk) * 256 + n0 + 4 * nq];
        }
        __syncthreads();
#pragma unroll
        for (int k = 0; k < 64; k++) {
            float4 a4 = *(const float4*)&As[k * 132 + 4 * tm];
            float4 b4 = *(const float4*)&Bs[k * 68 + 4 * tn];
            float av[4] = {a4.x, a4.y, a4.z, a4.w};
            float bv[4] = {b4.x, b4.y, b4.z, b4.w};
#pragma unroll
            for (int i = 0; i < 4; i++)
#pragma unroll
                for (int j = 0; j < 4; j++) acc[i][j] += av[i] * bv[j];
        }
        __syncthreads();
    }
#pragma unroll
    for (int i = 0; i < 4; i++) {
        int m = m0 + 4 * tm + i;
        float4 o = {acc[i][0], acc[i][1], acc[i][2], acc[i][3]};
        *(float4*)&out[((size_t)b * 2048 + m) * 256 + n0 + 4 * tn] = o;
    }
}

// ============ fused launches (32 scan blocks + filler blocks) ============
__global__ __launch_bounds__(512) void fusedA_kernel(const float* __restrict__ Xg,
                                                     const unsigned* __restrict__ wpk,
                                                     float* __restrict__ H1,
                                                     const float* __restrict__ c,
                                                     const float* __restrict__ w2,
                                                     float* __restrict__ out_w) {
    extern __shared__ char smem[];
    if (blockIdx.x < 32) lstm_scan_body(Xg, wpk, H1, smem, blockIdx.x);
    else wwrite_body(c, w2, out_w, blockIdx.x - 32);
}

__global__ __launch_bounds__(512) void fusedB_kernel(const float* __restrict__ Xg,
                                                     const unsigned* __restrict__ wpk,
                                                     float* __restrict__ H1,
                                                     const float* __restrict__ wmat,
                                                     const float* __restrict__ x,
                                                     float* __restrict__ out_main) {
    extern __shared__ char smem[];
    if (blockIdx.x < 32) lstm_scan_body(Xg, wpk, H1, smem, blockIdx.x);
    else gemm_out_body(wmat, x, out_main, blockIdx.x - 32, smem);
}

// ============ projection: log_dur (H1 [b][s][256]) ============
__global__ void proj_kernel(const float* __restrict__ H2, const float* __restrict__ pw,
                            const float* __restrict__ pb, const unsigned char* __restrict__ mask,
                            float* __restrict__ out) {
    int row = blockIdx.x * 4 + (threadIdx.x >> 6);
    int lane = threadIdx.x & 63;
    float4 h = *reinterpret_cast<const float4*>(&H2[(size_t)row * 256 + lane * 4]);
    float4 w = *reinterpret_cast<const float4*>(&pw[lane * 4]);
    float v = h.x * w.x + h.y * w.y + h.z * w.z + h.w * w.w;
#pragma unroll
    for (int off = 32; off; off >>= 1) v += __shfl_xor(v, off);
    if (lane == 0) {
        float r = v + pb[0];
        r = r > 0.f ? r : 0.f;
        if (mask[row]) r = 0.f;
        out[row] = r;
    }
}

// ============ w2[b,t] = sum_s exp(-0.1 (t+1-c)^2) ============
__global__ void wsum_kernel(const float* __restrict__ c, float* __restrict__ w2) {
    int idx = blockIdx.x * 4 + (threadIdx.x >> 6);
    int lane = threadIdx.x & 63;
    int b = idx >> 11, t = idx & 2047;
    float tv = (float)(t + 1);
    const float* cb = c + b * 512;
    float sum = 0.f;
#pragma unroll
    for (int i = 0; i < 8; i++) {
        float d = tv - cb[lane + 64 * i];
        sum += __expf(-0.1f * d * d);
    }
#pragma unroll
    for (int off = 32; off; off >>= 1) sum += __shfl_xor(sum, off);
    if (lane == 0) w2[idx] = (sum == 0.f) ? 1.f : sum;
}

extern "C" void kernel_launch(void* const* d_in, const int* in_sizes, int n_in,
                              void* d_out, int out_size, void* d_ws, size_t ws_size,
                              hipStream_t stream) {
    const float* x = (const float*)d_in[0];
    const unsigned char* mask = (const unsigned char*)d_in[1];
    const float* dur = (const float*)d_in[2];
    const float* Wih0 = (const float*)d_in[3];
    const float* Whh0 = (const float*)d_in[4];
    const float* b0 = (const float*)d_in[5];
    const float* Wih1 = (const float*)d_in[6];
    const float* Whh1 = (const float*)d_in[7];
    const float* b1 = (const float*)d_in[8];
    const float* pw = (const float*)d_in[9];
    const float* pb = (const float*)d_in[10];

    float* out = (float*)d_out;
    float* ws = (float*)d_ws;
    float* c = ws + WS_C;
    float* w2 = ws + WS_W2;
    unsigned* wpk = (unsigned*)(ws + WS_WPK);
    float* Xg = ws + WS_XG;
    float* H1 = ws + WS_H1;

    float* out_main = out + OUT_MAIN;
    float* out_logdur = out + OUT_LOGDUR;
    float* out_dur = out + OUT_DUR;
    float* out_w = out + OUT_W;

    // ---- prep: centers, duration copy, Whh f16 pack, w2 ----
    prep_kernel<<<16, 512, 0, stream>>>(dur, c, out_dur);
    whh_pack_kernel<<<512, 256, 0, stream>>>(Whh0, Whh1, wpk);
    wsum_kernel<<<8192, 256, 0, stream>>>(c, w2);

    // ---- layer 0: Xg gemm (A = x), then scan fused with w-write ----
    gemm_xg_kernel<<<dim3(128, 16), 256, 0, stream>>>(x, Wih0, b0, Xg);
    fusedA_kernel<<<32 + 4096, 512, 1024, stream>>>(Xg, wpk, H1, c, w2, out_w);

    // ---- layer 1: Xg gemm (A = H1, same row order), then scan fused with einsum ----
    gemm_xg_kernel<<<dim3(128, 16), 256, 0, stream>>>(H1, Wih1, b1, Xg);
    fusedB_kernel<<<32 + 1024, 512, 51200, stream>>>(Xg, wpk + 65536, H1, out_w, x, out_main);

    // ---- projection ----
    proj_kernel<<<2048, 256, 0, stream>>>(H1, pw, pb, mask, out_logdur);
}